// Round 1
// baseline (1124.817 us; speedup 1.0000x reference)
//
#include <hip/hip_runtime.h>
#include <hip/hip_bf16.h>

#define N_NODES 50000
#define N_EDGES 800000
#define N_REL 8
#define N_BASES 16
#define D 128  // D_IN == D_OUT == 128

// ---------------------------------------------------------------------------
// W[r,i,o] = sum_b coeff[r,b] * bases[b,i,o]
__global__ __launch_bounds__(256) void k_compute_W(const float* __restrict__ coeff,
                                                   const float* __restrict__ bases,
                                                   float* __restrict__ W) {
    int idx = blockIdx.x * 256 + threadIdx.x;      // r*16384 + i*128 + o
    int r = idx >> 14;
    int io = idx & 16383;
    float s = 0.f;
#pragma unroll
    for (int b = 0; b < N_BASES; ++b)
        s += coeff[r * N_BASES + b] * bases[b * 16384 + io];
    W[idx] = s;
}

// ---------------------------------------------------------------------------
// deg[et*N + dst] += 1
__global__ __launch_bounds__(256) void k_deg(const int* __restrict__ ei,
                                             const int* __restrict__ et,
                                             float* __restrict__ deg) {
    int i = blockIdx.x * blockDim.x + threadIdx.x;
    int stride = gridDim.x * blockDim.x;
    for (int e = i; e < N_EDGES; e += stride)
        atomicAdd(&deg[et[e] * N_NODES + ei[N_EDGES + e]], 1.0f);
}

// ---------------------------------------------------------------------------
// C[M,128] = A[M,128] @ B[128,128]   (fp32, 64x64 tile, 4x4 per thread)
__global__ __launch_bounds__(256) void k_gemm(const float* __restrict__ A,
                                              const float* __restrict__ B,
                                              float* __restrict__ C, int M) {
    __shared__ __attribute__((aligned(16))) float xs[64][132];  // +4 pad: breaks 4-way bank conflict on broadcast reads
    __shared__ __attribute__((aligned(16))) float ws[128][64];
    const int rb = blockIdx.x * 64;
    const int cb = blockIdx.y * 64;
    const int t = threadIdx.x;

    // load A tile: 64 rows x 128 cols (float4 x 8 per thread)
#pragma unroll
    for (int i = 0; i < 8; ++i) {
        int f = t + i * 256;          // float4 index, 2048 total
        int row = f >> 5;             // 32 float4 per row
        int c4 = (f & 31) << 2;
        float4 v = make_float4(0.f, 0.f, 0.f, 0.f);
        int gr = rb + row;
        if (gr < M) v = *(const float4*)&A[gr * D + c4];
        *(float4*)&xs[row][c4] = v;
    }
    // load B tile: 128 rows x 64 cols
#pragma unroll
    for (int i = 0; i < 8; ++i) {
        int f = t + i * 256;          // 2048 float4
        int row = f >> 4;             // 16 float4 per row
        int c4 = (f & 15) << 2;
        float4 v = *(const float4*)&B[row * D + cb + c4];
        *(float4*)&ws[row][c4] = v;
    }
    __syncthreads();

    const int c0 = (t & 15) << 2;
    const int r0 = (t >> 4) << 2;
    float acc[4][4] = {};
#pragma unroll 4
    for (int k = 0; k < 128; ++k) {
        float4 b = *(float4*)&ws[k][c0];
#pragma unroll
        for (int j = 0; j < 4; ++j) {
            float a = xs[r0 + j][k];
            acc[j][0] += a * b.x;
            acc[j][1] += a * b.y;
            acc[j][2] += a * b.z;
            acc[j][3] += a * b.w;
        }
    }
#pragma unroll
    for (int j = 0; j < 4; ++j) {
        int gr = rb + r0 + j;
        if (gr < M) {
            float4 v = make_float4(acc[j][0], acc[j][1], acc[j][2], acc[j][3]);
            *(float4*)&C[gr * D + cb + c0] = v;
        }
    }
}

// ---------------------------------------------------------------------------
// for edges with et==rel: out[dst] += xWr[src] * (1/max(deg[rel,dst],1))
__global__ __launch_bounds__(256) void k_scatter(const float* __restrict__ xWr,
                                                 const int* __restrict__ ei,
                                                 const int* __restrict__ et,
                                                 const float* __restrict__ deg,
                                                 float* __restrict__ out, int rel) {
    // 128 threads per edge (thread = output dim), 2 edges per block, grid-stride
    int g = (blockIdx.x << 1) | (threadIdx.x >> 7);
    int d = threadIdx.x & 127;
    int stride = gridDim.x << 1;
    for (int e = g; e < N_EDGES; e += stride) {
        if (et[e] != rel) continue;
        int src = ei[e];
        int dst = ei[N_EDGES + e];
        float dinv = 1.0f / fmaxf(deg[rel * N_NODES + dst], 1.0f);
        float v = xWr[src * D + d] * dinv;
        atomicAdd(&out[dst * D + d], v);
    }
}

// ---------------------------------------------------------------------------
extern "C" void kernel_launch(void* const* d_in, const int* in_sizes, int n_in,
                              void* d_out, int out_size, void* d_ws, size_t ws_size,
                              hipStream_t stream) {
    const float* x         = (const float*)d_in[0];
    const float* bases     = (const float*)d_in[1];
    const float* coeff     = (const float*)d_in[2];
    const float* self_loop = (const float*)d_in[3];
    const int*   ei        = (const int*)d_in[4];
    const int*   et        = (const int*)d_in[5];
    float* out = (float*)d_out;

    char* ws = (char*)d_ws;
    float* W   = (float*)ws;                              // 8*128*128*4 = 512 KB
    float* deg = (float*)(ws + (512 << 10));              // 8*50000*4 = 1.6 MB
    float* xWr = (float*)(ws + (512 << 10) + (2 << 20));  // 50000*128*4 = 25.6 MB
    size_t need = (512 << 10) + (2 << 20) + (size_t)N_NODES * D * 4;
    if (ws_size < need) return;  // ws too small: fail loudly

    hipMemsetAsync(deg, 0, (size_t)N_REL * N_NODES * sizeof(float), stream);
    k_compute_W<<<512, 256, 0, stream>>>(coeff, bases, W);
    k_deg<<<1024, 256, 0, stream>>>(ei, et, deg);

    // out = x @ self_loop  (also initializes every element of out)
    k_gemm<<<dim3(782, 2), 256, 0, stream>>>(x, self_loop, out, N_NODES);

    for (int r = 0; r < N_REL; ++r) {
        k_gemm<<<dim3(782, 2), 256, 0, stream>>>(x, W + r * 16384, xWr, N_NODES);
        k_scatter<<<2048, 256, 0, stream>>>(xWr, ei, et, deg, out, r);
    }
}

// Round 2
// 721.442 us; speedup vs baseline: 1.5591x; 1.5591x over previous
//
#include <hip/hip_runtime.h>
#include <hip/hip_bf16.h>

#define N_NODES 50000
#define N_EDGES 800000
#define N_REL 8
#define N_BASES 16
#define D 128  // D_IN == D_OUT == 128

// ---------------------------------------------------------------------------
// W[r,i,o] = sum_b coeff[r,b] * bases[b,i,o]
__global__ __launch_bounds__(256) void k_compute_W(const float* __restrict__ coeff,
                                                   const float* __restrict__ bases,
                                                   float* __restrict__ W) {
    int idx = blockIdx.x * 256 + threadIdx.x;      // r*16384 + i*128 + o
    int r = idx >> 14;
    int io = idx & 16383;
    float s = 0.f;
#pragma unroll
    for (int b = 0; b < N_BASES; ++b)
        s += coeff[r * N_BASES + b] * bases[b * 16384 + io];
    W[idx] = s;
}

// ---------------------------------------------------------------------------
// deg[et*N + dst] += 1, plus global histogram cnt[8] of edge types
__global__ __launch_bounds__(256) void k_deg_hist(const int* __restrict__ ei,
                                                  const int* __restrict__ et,
                                                  float* __restrict__ deg,
                                                  int* __restrict__ cnt) {
    __shared__ int h[N_REL];
    if (threadIdx.x < N_REL) h[threadIdx.x] = 0;
    __syncthreads();
    int i = blockIdx.x * blockDim.x + threadIdx.x;
    int stride = gridDim.x * blockDim.x;
    for (int e = i; e < N_EDGES; e += stride) {
        int r = et[e];
        atomicAdd(&deg[r * N_NODES + ei[N_EDGES + e]], 1.0f);
        atomicAdd(&h[r], 1);
    }
    __syncthreads();
    if (threadIdx.x < N_REL) atomicAdd(&cnt[threadIdx.x], h[threadIdx.x]);
}

// ---------------------------------------------------------------------------
// tiny exclusive scan over 8 bins -> off[9], cursor[8]
__global__ void k_scan(const int* __restrict__ cnt, int* __restrict__ off,
                       int* __restrict__ cursor) {
    if (threadIdx.x == 0) {
        int s = 0;
        for (int b = 0; b < N_REL; ++b) {
            off[b] = s; cursor[b] = s; s += cnt[b];
        }
        off[N_REL] = s;
    }
}

// ---------------------------------------------------------------------------
// bucket edges by relation; record = (src, dst, bitcast(dinv), 0)
#define BCHUNK 2048
__global__ __launch_bounds__(256) void k_bucket(const int* __restrict__ ei,
                                                const int* __restrict__ et,
                                                const float* __restrict__ deg,
                                                int* __restrict__ cursor,
                                                int4* __restrict__ recs) {
    __shared__ int lcnt[N_REL], lbase[N_REL];
    const int base = blockIdx.x * BCHUNK;
    const int t = threadIdx.x;
    if (t < N_REL) lcnt[t] = 0;
    __syncthreads();
    int myr[8];
#pragma unroll
    for (int i = 0; i < 8; ++i) {
        int e = base + t + i * 256;
        if (e < N_EDGES) {
            int r = et[e];
            myr[i] = r;
            atomicAdd(&lcnt[r], 1);
        } else myr[i] = -1;
    }
    __syncthreads();
    if (t < N_REL) lbase[t] = atomicAdd(&cursor[t], lcnt[t]);
    __syncthreads();
    if (t < N_REL) lcnt[t] = 0;   // reuse as intra-block cursor
    __syncthreads();
#pragma unroll
    for (int i = 0; i < 8; ++i) {
        int r = myr[i];
        if (r < 0) continue;
        int e = base + t + i * 256;
        int src = ei[e];
        int dst = ei[N_EDGES + e];
        float dinv = 1.0f / fmaxf(deg[r * N_NODES + dst], 1.0f);
        int p = lbase[r] + atomicAdd(&lcnt[r], 1);
        recs[p] = make_int4(src, dst, __float_as_int(dinv), 0);
    }
}

// ---------------------------------------------------------------------------
// C[M,128] = A[M,128] @ B[128,128]   (fp32, 64x64 tile, 4x4 per thread)
__global__ __launch_bounds__(256) void k_gemm(const float* __restrict__ A,
                                              const float* __restrict__ B,
                                              float* __restrict__ C, int M) {
    __shared__ __attribute__((aligned(16))) float xs[64][132];
    __shared__ __attribute__((aligned(16))) float ws[128][64];
    const int rb = blockIdx.x * 64;
    const int cb = blockIdx.y * 64;
    const int t = threadIdx.x;

#pragma unroll
    for (int i = 0; i < 8; ++i) {
        int f = t + i * 256;
        int row = f >> 5;
        int c4 = (f & 31) << 2;
        float4 v = make_float4(0.f, 0.f, 0.f, 0.f);
        int gr = rb + row;
        if (gr < M) v = *(const float4*)&A[gr * D + c4];
        *(float4*)&xs[row][c4] = v;
    }
#pragma unroll
    for (int i = 0; i < 8; ++i) {
        int f = t + i * 256;
        int row = f >> 4;
        int c4 = (f & 15) << 2;
        float4 v = *(const float4*)&B[row * D + cb + c4];
        *(float4*)&ws[row][c4] = v;
    }
    __syncthreads();

    const int c0 = (t & 15) << 2;
    const int r0 = (t >> 4) << 2;
    float acc[4][4] = {};
#pragma unroll 4
    for (int k = 0; k < 128; ++k) {
        float4 b = *(float4*)&ws[k][c0];
#pragma unroll
        for (int j = 0; j < 4; ++j) {
            float a = xs[r0 + j][k];
            acc[j][0] += a * b.x;
            acc[j][1] += a * b.y;
            acc[j][2] += a * b.z;
            acc[j][3] += a * b.w;
        }
    }
#pragma unroll
    for (int j = 0; j < 4; ++j) {
        int gr = rb + r0 + j;
        if (gr < M) {
            float4 v = make_float4(acc[j][0], acc[j][1], acc[j][2], acc[j][3]);
            *(float4*)&C[gr * D + cb + c0] = v;
        }
    }
}

// ---------------------------------------------------------------------------
// for bucketed edges [off[r], off[r+1]): out[dst] += xWr[src] * dinv
__global__ __launch_bounds__(256) void k_scatter(const float* __restrict__ xWr,
                                                 const int4* __restrict__ recs,
                                                 const int* __restrict__ off,
                                                 float* __restrict__ out, int rel) {
    const int start = off[rel];
    const int end = off[rel + 1];
    int g = (blockIdx.x << 1) | (threadIdx.x >> 7);
    int d = threadIdx.x & 127;
    int stride = gridDim.x << 1;
    for (int e = start + g; e < end; e += stride) {
        int4 rec = recs[e];
        float v = xWr[rec.x * D + d] * __int_as_float(rec.z);
        atomicAdd(&out[rec.y * D + d], v);
    }
}

// ---------------------------------------------------------------------------
extern "C" void kernel_launch(void* const* d_in, const int* in_sizes, int n_in,
                              void* d_out, int out_size, void* d_ws, size_t ws_size,
                              hipStream_t stream) {
    const float* x         = (const float*)d_in[0];
    const float* bases     = (const float*)d_in[1];
    const float* coeff     = (const float*)d_in[2];
    const float* self_loop = (const float*)d_in[3];
    const int*   ei        = (const int*)d_in[4];
    const int*   et        = (const int*)d_in[5];
    float* out = (float*)d_out;

    char* ws = (char*)d_ws;
    // layout
    float* W      = (float*)(ws + 0);                      // 512 KB
    float* deg    = (float*)(ws + 524288);                 // 1.6 MB (2 MB slot)
    int*   cnt    = (int*)  (ws + 2621440);                // 8 ints
    int*   off    = (int*)  (ws + 2621440 + 64);           // 9 ints
    int*   cursor = (int*)  (ws + 2621440 + 128);          // 8 ints
    int4*  recs   = (int4*) (ws + 2621696);                // 12.8 MB
    float* xWr    = (float*)(ws + 2621696 + 12800000);     // 25.6 MB
    size_t need = 2621696 + 12800000 + (size_t)N_NODES * D * 4;
    if (ws_size < need) return;

    // zero deg + meta
    hipMemsetAsync(deg, 0, 2097152 + 256, stream);

    k_compute_W<<<512, 256, 0, stream>>>(coeff, bases, W);
    k_deg_hist<<<1024, 256, 0, stream>>>(ei, et, deg, cnt);
    k_scan<<<1, 64, 0, stream>>>(cnt, off, cursor);
    k_bucket<<<(N_EDGES + BCHUNK - 1) / BCHUNK, 256, 0, stream>>>(ei, et, deg, cursor, recs);

    // out = x @ self_loop  (also initializes every element of out)
    k_gemm<<<dim3(782, 2), 256, 0, stream>>>(x, self_loop, out, N_NODES);

    for (int r = 0; r < N_REL; ++r) {
        k_gemm<<<dim3(782, 2), 256, 0, stream>>>(x, W + r * 16384, xWr, N_NODES);
        k_scatter<<<2048, 256, 0, stream>>>(xWr, recs, off, out, r);
    }
}

// Round 3
// 347.117 us; speedup vs baseline: 3.2405x; 2.0784x over previous
//
#include <hip/hip_runtime.h>
#include <hip/hip_bf16.h>

#define N_NODES 50000
#define N_EDGES 800000
#define N_REL 8
#define N_BASES 16
#define D 128

typedef __attribute__((ext_vector_type(8))) short bf16x8;
typedef __attribute__((ext_vector_type(4))) float f32x4;

__device__ inline unsigned short f2bf(float f) {
    unsigned int x = __float_as_uint(f);
    unsigned int r = x + 0x7FFFu + ((x >> 16) & 1u);
    return (unsigned short)(r >> 16);
}
__device__ inline float bf2f(unsigned short u) {
    return __uint_as_float(((unsigned int)u) << 16);
}

// ---------------------------------------------------------------------------
// W[r,i,o] = sum_b coeff[r,b] * bases[b,i,o]   (fp32, [8][128][128])
__global__ __launch_bounds__(256) void k_compute_W(const float* __restrict__ coeff,
                                                   const float* __restrict__ bases,
                                                   float* __restrict__ W) {
    int idx = blockIdx.x * 256 + threadIdx.x;
    int r = idx >> 14;
    int io = idx & 16383;
    float s = 0.f;
#pragma unroll
    for (int b = 0; b < N_BASES; ++b)
        s += coeff[r * N_BASES + b] * bases[b * 16384 + io];
    W[idx] = s;
}

// ---------------------------------------------------------------------------
// WbT[r][o][i] = bf16( (r<8 ? W[r] : self_loop)[i][o] )  — transposed, bf16
__global__ __launch_bounds__(256) void k_transW(const float* __restrict__ W,
                                                const float* __restrict__ self_loop,
                                                unsigned short* __restrict__ WbT) {
    int r = blockIdx.x;  // 0..8
    const float* src = (r < 8) ? (W + r * 16384) : self_loop;
    __shared__ unsigned short t[128][129];
    for (int i = threadIdx.x; i < 16384; i += 256)
        t[i >> 7][i & 127] = f2bf(src[i]);          // t[i_idx][o]
    __syncthreads();
    for (int i = threadIdx.x; i < 16384; i += 256) {
        int o = i >> 7, k = i & 127;
        WbT[r * 16384 + o * 128 + k] = t[k][o];
    }
}

// ---------------------------------------------------------------------------
// xb = bf16(x)
__global__ __launch_bounds__(256) void k_cvtx(const float* __restrict__ x,
                                              unsigned short* __restrict__ xb) {
    int i = blockIdx.x * 256 + threadIdx.x;         // per 8 elements; grid exact
    const float4* xp = (const float4*)x;
    float4 a = xp[i * 2], b = xp[i * 2 + 1];
    int4 o;
    o.x = (int)f2bf(a.x) | ((int)f2bf(a.y) << 16);
    o.y = (int)f2bf(a.z) | ((int)f2bf(a.w) << 16);
    o.z = (int)f2bf(b.x) | ((int)f2bf(b.y) << 16);
    o.w = (int)f2bf(b.z) | ((int)f2bf(b.w) << 16);
    ((int4*)xb)[i] = o;
}

// ---------------------------------------------------------------------------
// deg[rel*N+dst] += 1 (fp32, exact small ints); cnt_dst[dst] += 1
__global__ __launch_bounds__(256) void k_hist(const int* __restrict__ ei,
                                              const int* __restrict__ et,
                                              float* __restrict__ deg,
                                              int* __restrict__ cnt_dst) {
    int i = blockIdx.x * blockDim.x + threadIdx.x;
    int stride = gridDim.x * blockDim.x;
    for (int e = i; e < N_EDGES; e += stride) {
        int r = et[e];
        int dst = ei[N_EDGES + e];
        atomicAdd(&deg[r * N_NODES + dst], 1.0f);
        atomicAdd(&cnt_dst[dst], 1);
    }
}

// ---------------------------------------------------------------------------
// exclusive scan of cnt_dst[50000] -> row_off[50001], cursor[50000]
__global__ __launch_bounds__(1024) void k_scan(const int* __restrict__ cnt,
                                               int* __restrict__ row_off,
                                               int* __restrict__ cursor) {
    __shared__ int s[1024];
    __shared__ int base;
    int t = threadIdx.x;
    if (t == 0) base = 0;
    __syncthreads();
    for (int c = 0; c < 49; ++c) {                  // 49*1024 = 50176 >= 50000
        int i = c * 1024 + t;
        int v = (i < N_NODES) ? cnt[i] : 0;
        s[t] = v;
        __syncthreads();
        for (int off = 1; off < 1024; off <<= 1) {  // inclusive scan
            int x = (t >= off) ? s[t - off] : 0;
            __syncthreads();
            s[t] += x;
            __syncthreads();
        }
        if (i < N_NODES) {
            int ex = base + s[t] - v;
            row_off[i] = ex;
            cursor[i] = ex;
        }
        __syncthreads();                            // all reads of base done
        if (t == 0) base += s[1023];
        __syncthreads();
    }
    if (t == 0) row_off[N_NODES] = base;
}

// ---------------------------------------------------------------------------
// csr[pos] = src | (rel<<16)   (src < 65536, rel < 8)
__global__ __launch_bounds__(256) void k_fill(const int* __restrict__ ei,
                                              const int* __restrict__ et,
                                              int* __restrict__ cursor,
                                              int* __restrict__ csr) {
    int i = blockIdx.x * blockDim.x + threadIdx.x;
    int stride = gridDim.x * blockDim.x;
    for (int e = i; e < N_EDGES; e += stride) {
        int src = ei[e];
        int dst = ei[N_EDGES + e];
        int r = et[e];
        int p = atomicAdd(&cursor[dst], 1);
        csr[p] = src | (r << 16);
    }
}

// ---------------------------------------------------------------------------
// C[M x 128*gridDim.y] = bf16 MFMA GEMM: A=xb [M][128] bf16, B panel per y from
// Bbase + y*16384 (bf16, [o][k] transposed layout). Output col = y*128 + col.
// OB: write bf16 to Obf with row stride `ostride`; else fp32 to Of.
template <bool OB>
__global__ __launch_bounds__(256) void k_mm(const unsigned short* __restrict__ xb,
                                            const unsigned short* __restrict__ Bbase,
                                            unsigned short* __restrict__ Obf,
                                            float* __restrict__ Of,
                                            int ostride, int M) {
    __shared__ unsigned short As[64][136];
    __shared__ unsigned short Bs[128][136];
    const int rb = blockIdx.x * 64;
    const unsigned short* Bsrc = Bbase + blockIdx.y * 16384;
    const int t = threadIdx.x;

    // stage A: 64x128 bf16 (1024 16B-chunks)
#pragma unroll
    for (int i = 0; i < 4; ++i) {
        int f = t + i * 256;
        int row = f >> 4, c8 = (f & 15) << 3;
        int gr = rb + row;
        int4 v = make_int4(0, 0, 0, 0);
        if (gr < M) v = *(const int4*)&xb[gr * D + c8];
        *(int4*)&As[row][c8] = v;
    }
    // stage B: 128x128 bf16 (2048 16B-chunks)
#pragma unroll
    for (int i = 0; i < 8; ++i) {
        int f = t + i * 256;
        int row = f >> 4, c8 = (f & 15) << 3;
        int4 v = *(const int4*)&Bsrc[row * 128 + c8];
        *(int4*)&Bs[row][c8] = v;
    }
    __syncthreads();

    const int lane = t & 63;
    const int w = t >> 6;          // wave: cols [w*32, w*32+32)
    const int lr = lane & 15;
    const int lg = lane >> 4;
    f32x4 acc[4][2] = {};
#pragma unroll
    for (int kk = 0; kk < 128; kk += 32) {
        int ko = kk + lg * 8;
        bf16x8 a[4], b[2];
#pragma unroll
        for (int m = 0; m < 4; ++m) a[m] = *(const bf16x8*)&As[m * 16 + lr][ko];
#pragma unroll
        for (int n = 0; n < 2; ++n) b[n] = *(const bf16x8*)&Bs[w * 32 + n * 16 + lr][ko];
#pragma unroll
        for (int m = 0; m < 4; ++m)
#pragma unroll
            for (int n = 0; n < 2; ++n)
                acc[m][n] = __builtin_amdgcn_mfma_f32_16x16x32_bf16(a[m], b[n], acc[m][n], 0, 0, 0);
    }

#pragma unroll
    for (int m = 0; m < 4; ++m)
#pragma unroll
        for (int n = 0; n < 2; ++n)
#pragma unroll
            for (int q = 0; q < 4; ++q) {
                int grow = rb + m * 16 + lg * 4 + q;
                int col = blockIdx.y * 128 + w * 32 + n * 16 + lr;
                if (grow < M) {
                    if (OB) Obf[(size_t)grow * ostride + col] = f2bf(acc[m][n][q]);
                    else    Of[(size_t)grow * ostride + col] = acc[m][n][q];
                }
            }
}

// ---------------------------------------------------------------------------
// big path: one block per dst; out[dst] += sum over csr segment of
//           xWall[src][rel*128+d] * dinv[rel]
__global__ __launch_bounds__(128) void k_gather(const unsigned short* __restrict__ xWall,
                                                const int* __restrict__ csr,
                                                const int* __restrict__ row_off,
                                                const float* __restrict__ deg,
                                                float* __restrict__ out) {
    const int dst = blockIdx.x;
    const int t = threadIdx.x;
    __shared__ float sdinv[N_REL];
    __shared__ int epack[128];
    int s0 = row_off[dst], s1 = row_off[dst + 1];
    int n = s1 - s0;
    if (n <= 0) return;
    if (t < N_REL) sdinv[t] = 1.0f / fmaxf(deg[t * N_NODES + dst], 1.0f);
    float acc = 0.f;
    for (int base = 0; base < n; base += 128) {
        int m = min(n - base, 128);
        if (t < m) epack[t] = csr[s0 + base + t];
        __syncthreads();
        for (int j = 0; j < m; ++j) {
            int p = epack[j];
            int src = p & 0xFFFF;
            int rel = p >> 16;
            acc += sdinv[rel] * bf2f(xWall[(size_t)src * 1024 + rel * 128 + t]);
        }
        __syncthreads();
    }
    out[dst * D + t] += acc;
}

// ---------------------------------------------------------------------------
// fallback: per-relation gather from xWr [N][128] bf16
__global__ __launch_bounds__(128) void k_gather_r(const unsigned short* __restrict__ xWr,
                                                  const int* __restrict__ csr,
                                                  const int* __restrict__ row_off,
                                                  const float* __restrict__ deg,
                                                  float* __restrict__ out, int rel) {
    const int dst = blockIdx.x;
    const int t = threadIdx.x;
    __shared__ int epack[128];
    int s0 = row_off[dst], s1 = row_off[dst + 1];
    int n = s1 - s0;
    if (n <= 0) return;
    float dinv = 1.0f / fmaxf(deg[rel * N_NODES + dst], 1.0f);
    float acc = 0.f;
    for (int base = 0; base < n; base += 128) {
        int m = min(n - base, 128);
        if (t < m) epack[t] = csr[s0 + base + t];
        __syncthreads();
        for (int j = 0; j < m; ++j) {
            int p = epack[j];
            if ((p >> 16) != rel) continue;
            acc += bf2f(xWr[(size_t)(p & 0xFFFF) * 128 + t]);
        }
        __syncthreads();
    }
    if (acc != 0.f || true) out[dst * D + t] += acc * dinv;
}

// ---------------------------------------------------------------------------
extern "C" void kernel_launch(void* const* d_in, const int* in_sizes, int n_in,
                              void* d_out, int out_size, void* d_ws, size_t ws_size,
                              hipStream_t stream) {
    const float* x         = (const float*)d_in[0];
    const float* bases     = (const float*)d_in[1];
    const float* coeff     = (const float*)d_in[2];
    const float* self_loop = (const float*)d_in[3];
    const int*   ei        = (const int*)d_in[4];
    const int*   et        = (const int*)d_in[5];
    float* out = (float*)d_out;

    char* ws = (char*)d_ws;
    size_t o = 0;
    auto alloc = [&](size_t bytes) { size_t r = o; o += (bytes + 255) & ~(size_t)255; return r; };
    size_t o_deg    = alloc((size_t)N_REL * N_NODES * 4);   // zeroed
    size_t o_cnt    = alloc((size_t)N_NODES * 4);           // zeroed
    size_t zero_end = o;
    size_t o_cursor = alloc((size_t)N_NODES * 4);
    size_t o_rowoff = alloc((size_t)(N_NODES + 1) * 4);
    size_t o_csr    = alloc((size_t)N_EDGES * 4);
    size_t o_W      = alloc((size_t)N_REL * 16384 * 4);
    size_t o_WbT    = alloc((size_t)9 * 16384 * 2);
    size_t o_xb     = alloc((size_t)N_NODES * D * 2);
    size_t o_xW     = o;                                     // big: N*1024*2 ; small: N*128*2
    size_t need_big   = o + (size_t)N_NODES * 1024 * 2;
    size_t need_small = o + (size_t)N_NODES * 128 * 2;
    if (ws_size < need_small) return;
    bool big = (ws_size >= need_big);

    float*          deg     = (float*)(ws + o_deg);
    int*            cnt     = (int*)(ws + o_cnt);
    int*            cursor  = (int*)(ws + o_cursor);
    int*            row_off = (int*)(ws + o_rowoff);
    int*            csr     = (int*)(ws + o_csr);
    float*          W       = (float*)(ws + o_W);
    unsigned short* WbT     = (unsigned short*)(ws + o_WbT);
    unsigned short* xb      = (unsigned short*)(ws + o_xb);
    unsigned short* xW      = (unsigned short*)(ws + o_xW);

    hipMemsetAsync(ws, 0, zero_end, stream);

    k_compute_W<<<512, 256, 0, stream>>>(coeff, bases, W);
    k_transW<<<9, 256, 0, stream>>>(W, self_loop, WbT);
    k_cvtx<<<(N_NODES * D / 8 + 255) / 256, 256, 0, stream>>>(x, xb);
    k_hist<<<1024, 256, 0, stream>>>(ei, et, deg, cnt);
    k_scan<<<1, 1024, 0, stream>>>(cnt, row_off, cursor);
    k_fill<<<1024, 256, 0, stream>>>(ei, et, cursor, csr);

    const int MB = (N_NODES + 63) / 64;  // 782

    // self-loop GEMM -> fp32 out (initializes every element)
    k_mm<false><<<dim3(MB, 1), 256, 0, stream>>>(xb, WbT + 8 * 16384, nullptr, out, 128, N_NODES);

    if (big) {
        k_mm<true><<<dim3(MB, 8), 256, 0, stream>>>(xb, WbT, xW, nullptr, 1024, N_NODES);
        k_gather<<<N_NODES, 128, 0, stream>>>(xW, csr, row_off, deg, out);
    } else {
        for (int r = 0; r < N_REL; ++r) {
            k_mm<true><<<dim3(MB, 1), 256, 0, stream>>>(xb, WbT + r * 16384, xW, nullptr, 128, N_NODES);
            k_gather_r<<<N_NODES, 128, 0, stream>>>(xW, csr, row_off, deg, out, r);
        }
    }
}

// Round 4
// 269.525 us; speedup vs baseline: 4.1733x; 1.2879x over previous
//
#include <hip/hip_runtime.h>
#include <hip/hip_bf16.h>

#define N_NODES 50000
#define N_EDGES 800000
#define N_REL 8
#define N_BASES 16
#define D 128

typedef __attribute__((ext_vector_type(8))) short bf16x8;
typedef __attribute__((ext_vector_type(4))) float f32x4;

__device__ inline unsigned short f2bf(float f) {
    unsigned int x = __float_as_uint(f);
    unsigned int r = x + 0x7FFFu + ((x >> 16) & 1u);
    return (unsigned short)(r >> 16);
}
__device__ inline float bf2f(unsigned short u) {
    return __uint_as_float(((unsigned int)u) << 16);
}

// ---------------------------------------------------------------------------
// W[r,i,o] = sum_b coeff[r,b] * bases[b,i,o]   (fp32, [8][128][128])
__global__ __launch_bounds__(256) void k_compute_W(const float* __restrict__ coeff,
                                                   const float* __restrict__ bases,
                                                   float* __restrict__ W) {
    int idx = blockIdx.x * 256 + threadIdx.x;
    int r = idx >> 14;
    int io = idx & 16383;
    float s = 0.f;
#pragma unroll
    for (int b = 0; b < N_BASES; ++b)
        s += coeff[r * N_BASES + b] * bases[b * 16384 + io];
    W[idx] = s;
}

// ---------------------------------------------------------------------------
// WbT[r][o][i] = bf16( (r<8 ? W[r] : self_loop)[i][o] )  — transposed, bf16
__global__ __launch_bounds__(256) void k_transW(const float* __restrict__ W,
                                                const float* __restrict__ self_loop,
                                                unsigned short* __restrict__ WbT) {
    int r = blockIdx.x;  // 0..8
    const float* src = (r < 8) ? (W + r * 16384) : self_loop;
    __shared__ unsigned short t[128][129];
    for (int i = threadIdx.x; i < 16384; i += 256)
        t[i >> 7][i & 127] = f2bf(src[i]);          // t[i_idx][o]
    __syncthreads();
    for (int i = threadIdx.x; i < 16384; i += 256) {
        int o = i >> 7, k = i & 127;
        WbT[r * 16384 + o * 128 + k] = t[k][o];
    }
}

// ---------------------------------------------------------------------------
// xb = bf16(x)
__global__ __launch_bounds__(256) void k_cvtx(const float* __restrict__ x,
                                              unsigned short* __restrict__ xb) {
    int i = blockIdx.x * 256 + threadIdx.x;         // per 8 elements; grid exact
    const float4* xp = (const float4*)x;
    float4 a = xp[i * 2], b = xp[i * 2 + 1];
    int4 o;
    o.x = (int)f2bf(a.x) | ((int)f2bf(a.y) << 16);
    o.y = (int)f2bf(a.z) | ((int)f2bf(a.w) << 16);
    o.z = (int)f2bf(b.x) | ((int)f2bf(b.y) << 16);
    o.w = (int)f2bf(b.z) | ((int)f2bf(b.w) << 16);
    ((int4*)xb)[i] = o;
}

// ---------------------------------------------------------------------------
// deg[rel*N+dst] += 1 (fp32, exact small ints); cnt_dst[dst] += 1
__global__ __launch_bounds__(256) void k_hist(const int* __restrict__ ei,
                                              const int* __restrict__ et,
                                              float* __restrict__ deg,
                                              int* __restrict__ cnt_dst) {
    int i = blockIdx.x * blockDim.x + threadIdx.x;
    int stride = gridDim.x * blockDim.x;
    for (int e = i; e < N_EDGES; e += stride) {
        int r = et[e];
        int dst = ei[N_EDGES + e];
        atomicAdd(&deg[r * N_NODES + dst], 1.0f);
        atomicAdd(&cnt_dst[dst], 1);
    }
}

// ---------------------------------------------------------------------------
// 3-phase device-wide exclusive scan of cnt[50000] -> row_off[50001], cursor
#define SCAN_BLOCKS 49  // 49 * 1024 = 50176 >= 50000

__global__ __launch_bounds__(256) void k_scan1(const int* __restrict__ cnt,
                                               int* __restrict__ bsum) {
    int b = blockIdx.x, t = threadIdx.x;
    int idx4 = b * 1024 + t * 4;
    int s = 0;
#pragma unroll
    for (int i = 0; i < 4; ++i) {
        int idx = idx4 + i;
        if (idx < N_NODES) s += cnt[idx];
    }
#pragma unroll
    for (int off = 32; off; off >>= 1) s += __shfl_down(s, off);
    __shared__ int wsums[4];
    int lane = t & 63, wv = t >> 6;
    if (lane == 0) wsums[wv] = s;
    __syncthreads();
    if (t == 0) bsum[b] = wsums[0] + wsums[1] + wsums[2] + wsums[3];
}

__global__ void k_scan2(const int* __restrict__ bsum, int* __restrict__ bbase) {
    if (threadIdx.x == 0) {
        int s = 0;
        for (int i = 0; i < SCAN_BLOCKS; ++i) { bbase[i] = s; s += bsum[i]; }
        bbase[SCAN_BLOCKS] = s;
    }
}

__global__ __launch_bounds__(256) void k_scan3(const int* __restrict__ cnt,
                                               const int* __restrict__ bbase,
                                               int* __restrict__ row_off,
                                               int* __restrict__ cursor) {
    int b = blockIdx.x, t = threadIdx.x;
    int idx4 = b * 1024 + t * 4;
    int vals[4], pre[4];
    int tsum = 0;
#pragma unroll
    for (int i = 0; i < 4; ++i) {
        int idx = idx4 + i;
        vals[i] = (idx < N_NODES) ? cnt[idx] : 0;
        pre[i] = tsum;
        tsum += vals[i];
    }
    // inclusive wave scan of tsum
    int lane = t & 63, wv = t >> 6;
    int inc = tsum;
#pragma unroll
    for (int off = 1; off < 64; off <<= 1) {
        int y = __shfl_up(inc, off);
        if (lane >= off) inc += y;
    }
    __shared__ int wsums[4];
    if (lane == 63) wsums[wv] = inc;
    __syncthreads();
    int wbase = 0;
    for (int i = 0; i < wv; ++i) wbase += wsums[i];
    int ex = wbase + inc - tsum;            // exclusive prefix within block
    int gbase = bbase[b] + ex;
#pragma unroll
    for (int i = 0; i < 4; ++i) {
        int idx = idx4 + i;
        if (idx < N_NODES) {
            int e = gbase + pre[i];
            row_off[idx] = e;
            cursor[idx] = e;
        }
    }
    if (b == 0 && t == 0) row_off[N_NODES] = bbase[SCAN_BLOCKS];
}

// ---------------------------------------------------------------------------
// csr[pos] = src | (rel<<16)   (src < 65536, rel < 8)
__global__ __launch_bounds__(256) void k_fill(const int* __restrict__ ei,
                                              const int* __restrict__ et,
                                              int* __restrict__ cursor,
                                              int* __restrict__ csr) {
    int i = blockIdx.x * blockDim.x + threadIdx.x;
    int stride = gridDim.x * blockDim.x;
    for (int e = i; e < N_EDGES; e += stride) {
        int src = ei[e];
        int dst = ei[N_EDGES + e];
        int r = et[e];
        int p = atomicAdd(&cursor[dst], 1);
        csr[p] = src | (r << 16);
    }
}

// ---------------------------------------------------------------------------
// C[M x 128*gridDim.y] = bf16 MFMA GEMM: A=xb [M][128] bf16, B panel per y from
// Bbase + y*16384 (bf16, [o][k] transposed layout). Output col = y*128 + col.
template <bool OB>
__global__ __launch_bounds__(256) void k_mm(const unsigned short* __restrict__ xb,
                                            const unsigned short* __restrict__ Bbase,
                                            unsigned short* __restrict__ Obf,
                                            float* __restrict__ Of,
                                            int ostride, int M) {
    __shared__ unsigned short As[64][136];
    __shared__ unsigned short Bs[128][136];
    const int rb = blockIdx.x * 64;
    const unsigned short* Bsrc = Bbase + blockIdx.y * 16384;
    const int t = threadIdx.x;

#pragma unroll
    for (int i = 0; i < 4; ++i) {
        int f = t + i * 256;
        int row = f >> 4, c8 = (f & 15) << 3;
        int gr = rb + row;
        int4 v = make_int4(0, 0, 0, 0);
        if (gr < M) v = *(const int4*)&xb[gr * D + c8];
        *(int4*)&As[row][c8] = v;
    }
#pragma unroll
    for (int i = 0; i < 8; ++i) {
        int f = t + i * 256;
        int row = f >> 4, c8 = (f & 15) << 3;
        int4 v = *(const int4*)&Bsrc[row * 128 + c8];
        *(int4*)&Bs[row][c8] = v;
    }
    __syncthreads();

    const int lane = t & 63;
    const int w = t >> 6;
    const int lr = lane & 15;
    const int lg = lane >> 4;
    f32x4 acc[4][2] = {};
#pragma unroll
    for (int kk = 0; kk < 128; kk += 32) {
        int ko = kk + lg * 8;
        bf16x8 a[4], b[2];
#pragma unroll
        for (int m = 0; m < 4; ++m) a[m] = *(const bf16x8*)&As[m * 16 + lr][ko];
#pragma unroll
        for (int n = 0; n < 2; ++n) b[n] = *(const bf16x8*)&Bs[w * 32 + n * 16 + lr][ko];
#pragma unroll
        for (int m = 0; m < 4; ++m)
#pragma unroll
            for (int n = 0; n < 2; ++n)
                acc[m][n] = __builtin_amdgcn_mfma_f32_16x16x32_bf16(a[m], b[n], acc[m][n], 0, 0, 0);
    }

#pragma unroll
    for (int m = 0; m < 4; ++m)
#pragma unroll
        for (int n = 0; n < 2; ++n)
#pragma unroll
            for (int q = 0; q < 4; ++q) {
                int grow = rb + m * 16 + lg * 4 + q;
                int col = blockIdx.y * 128 + w * 32 + n * 16 + lr;
                if (grow < M) {
                    if (OB) Obf[(size_t)grow * ostride + col] = f2bf(acc[m][n][q]);
                    else    Of[(size_t)grow * ostride + col] = acc[m][n][q];
                }
            }
}

// ---------------------------------------------------------------------------
// big path: one block per dst; out[dst] += sum over csr segment of
//           xWall[src][rel*128+d] * dinv[rel]
__global__ __launch_bounds__(128) void k_gather(const unsigned short* __restrict__ xWall,
                                                const int* __restrict__ csr,
                                                const int* __restrict__ row_off,
                                                const float* __restrict__ deg,
                                                float* __restrict__ out) {
    const int dst = blockIdx.x;
    const int t = threadIdx.x;
    __shared__ float sdinv[N_REL];
    __shared__ int epack[128];
    int s0 = row_off[dst], s1 = row_off[dst + 1];
    int n = s1 - s0;
    if (n <= 0) return;
    if (t < N_REL) sdinv[t] = 1.0f / fmaxf(deg[t * N_NODES + dst], 1.0f);
    float acc = 0.f;
    for (int base = 0; base < n; base += 128) {
        int m = min(n - base, 128);
        if (t < m) epack[t] = csr[s0 + base + t];
        __syncthreads();
        for (int j = 0; j < m; ++j) {
            int p = epack[j];
            int src = p & 0xFFFF;
            int rel = p >> 16;
            acc += sdinv[rel] * bf2f(xWall[(size_t)src * 1024 + rel * 128 + t]);
        }
        __syncthreads();
    }
    out[dst * D + t] += acc;
}

// ---------------------------------------------------------------------------
// fallback: per-relation gather from xWr [N][128] bf16
__global__ __launch_bounds__(128) void k_gather_r(const unsigned short* __restrict__ xWr,
                                                  const int* __restrict__ csr,
                                                  const int* __restrict__ row_off,
                                                  const float* __restrict__ deg,
                                                  float* __restrict__ out, int rel) {
    const int dst = blockIdx.x;
    const int t = threadIdx.x;
    __shared__ int epack[128];
    int s0 = row_off[dst], s1 = row_off[dst + 1];
    int n = s1 - s0;
    if (n <= 0) return;
    float dinv = 1.0f / fmaxf(deg[rel * N_NODES + dst], 1.0f);
    float acc = 0.f;
    for (int base = 0; base < n; base += 128) {
        int m = min(n - base, 128);
        if (t < m) epack[t] = csr[s0 + base + t];
        __syncthreads();
        for (int j = 0; j < m; ++j) {
            int p = epack[j];
            if ((p >> 16) != rel) continue;
            acc += bf2f(xWr[(size_t)(p & 0xFFFF) * 128 + t]);
        }
        __syncthreads();
    }
    out[dst * D + t] += acc * dinv;
}

// ---------------------------------------------------------------------------
extern "C" void kernel_launch(void* const* d_in, const int* in_sizes, int n_in,
                              void* d_out, int out_size, void* d_ws, size_t ws_size,
                              hipStream_t stream) {
    const float* x         = (const float*)d_in[0];
    const float* bases     = (const float*)d_in[1];
    const float* coeff     = (const float*)d_in[2];
    const float* self_loop = (const float*)d_in[3];
    const int*   ei        = (const int*)d_in[4];
    const int*   et        = (const int*)d_in[5];
    float* out = (float*)d_out;

    char* ws = (char*)d_ws;
    size_t o = 0;
    auto alloc = [&](size_t bytes) { size_t r = o; o += (bytes + 255) & ~(size_t)255; return r; };
    size_t o_deg    = alloc((size_t)N_REL * N_NODES * 4);   // zeroed
    size_t o_cnt    = alloc((size_t)N_NODES * 4);           // zeroed
    size_t zero_end = o;
    size_t o_cursor = alloc((size_t)N_NODES * 4);
    size_t o_rowoff = alloc((size_t)(N_NODES + 1) * 4);
    size_t o_bsum   = alloc((size_t)SCAN_BLOCKS * 4);
    size_t o_bbase  = alloc((size_t)(SCAN_BLOCKS + 1) * 4);
    size_t o_csr    = alloc((size_t)N_EDGES * 4);
    size_t o_W      = alloc((size_t)N_REL * 16384 * 4);
    size_t o_WbT    = alloc((size_t)9 * 16384 * 2);
    size_t o_xb     = alloc((size_t)N_NODES * D * 2);
    size_t o_xW     = o;
    size_t need_big   = o + (size_t)N_NODES * 1024 * 2;
    size_t need_small = o + (size_t)N_NODES * 128 * 2;
    if (ws_size < need_small) return;
    bool big = (ws_size >= need_big);

    float*          deg     = (float*)(ws + o_deg);
    int*            cnt     = (int*)(ws + o_cnt);
    int*            cursor  = (int*)(ws + o_cursor);
    int*            row_off = (int*)(ws + o_rowoff);
    int*            bsum    = (int*)(ws + o_bsum);
    int*            bbase   = (int*)(ws + o_bbase);
    int*            csr     = (int*)(ws + o_csr);
    float*          W       = (float*)(ws + o_W);
    unsigned short* WbT     = (unsigned short*)(ws + o_WbT);
    unsigned short* xb      = (unsigned short*)(ws + o_xb);
    unsigned short* xW      = (unsigned short*)(ws + o_xW);

    hipMemsetAsync(ws, 0, zero_end, stream);

    k_compute_W<<<512, 256, 0, stream>>>(coeff, bases, W);
    k_transW<<<9, 256, 0, stream>>>(W, self_loop, WbT);
    k_cvtx<<<(N_NODES * D / 8 + 255) / 256, 256, 0, stream>>>(x, xb);
    k_hist<<<1024, 256, 0, stream>>>(ei, et, deg, cnt);
    k_scan1<<<SCAN_BLOCKS, 256, 0, stream>>>(cnt, bsum);
    k_scan2<<<1, 64, 0, stream>>>(bsum, bbase);
    k_scan3<<<SCAN_BLOCKS, 256, 0, stream>>>(cnt, bbase, row_off, cursor);
    k_fill<<<1024, 256, 0, stream>>>(ei, et, cursor, csr);

    const int MB = (N_NODES + 63) / 64;  // 782

    // self-loop GEMM -> fp32 out (initializes every element)
    k_mm<false><<<dim3(MB, 1), 256, 0, stream>>>(xb, WbT + 8 * 16384, nullptr, out, 128, N_NODES);

    if (big) {
        k_mm<true><<<dim3(MB, 8), 256, 0, stream>>>(xb, WbT, xW, nullptr, 1024, N_NODES);
        k_gather<<<N_NODES, 128, 0, stream>>>(xW, csr, row_off, deg, out);
    } else {
        for (int r = 0; r < N_REL; ++r) {
            k_mm<true><<<dim3(MB, 1), 256, 0, stream>>>(xb, WbT + r * 16384, xW, nullptr, 128, N_NODES);
            k_gather_r<<<N_NODES, 128, 0, stream>>>(xW, csr, row_off, deg, out, r);
        }
    }
}

// Round 5
// 168.462 us; speedup vs baseline: 6.6770x; 1.5999x over previous
//
#include <hip/hip_runtime.h>
#include <hip/hip_bf16.h>

#define N_NODES 50000
#define N_EDGES 800000
#define N_REL 8
#define N_BASES 16
#define D 128
#define NCB 196   // coarse buckets = ceil(N_NODES/256)

typedef __attribute__((ext_vector_type(8))) short bf16x8;
typedef __attribute__((ext_vector_type(4))) float f32x4;

__device__ inline unsigned short f2bf(float f) {
    unsigned int x = __float_as_uint(f);
    unsigned int r = x + 0x7FFFu + ((x >> 16) & 1u);
    return (unsigned short)(r >> 16);
}
__device__ inline float bf2f(unsigned short u) {
    return __uint_as_float(((unsigned int)u) << 16);
}

// ---------------------------------------------------------------------------
// W[r,i,o] = sum_b coeff[r,b] * bases[b,i,o]   (fp32, [8][128][128])
__global__ __launch_bounds__(256) void k_compute_W(const float* __restrict__ coeff,
                                                   const float* __restrict__ bases,
                                                   float* __restrict__ W) {
    int idx = blockIdx.x * 256 + threadIdx.x;
    int r = idx >> 14;
    int io = idx & 16383;
    float s = 0.f;
#pragma unroll
    for (int b = 0; b < N_BASES; ++b)
        s += coeff[r * N_BASES + b] * bases[b * 16384 + io];
    W[idx] = s;
}

// ---------------------------------------------------------------------------
// WbT[r][o][i] = bf16( (r<8 ? W[r] : self_loop)[i][o] )  — transposed, bf16
__global__ __launch_bounds__(256) void k_transW(const float* __restrict__ W,
                                                const float* __restrict__ self_loop,
                                                unsigned short* __restrict__ WbT) {
    int r = blockIdx.x;  // 0..8
    const float* src = (r < 8) ? (W + r * 16384) : self_loop;
    __shared__ unsigned short t[128][129];
    for (int i = threadIdx.x; i < 16384; i += 256)
        t[i >> 7][i & 127] = f2bf(src[i]);
    __syncthreads();
    for (int i = threadIdx.x; i < 16384; i += 256) {
        int o = i >> 7, k = i & 127;
        WbT[r * 16384 + o * 128 + k] = t[k][o];
    }
}

// ---------------------------------------------------------------------------
// xb = bf16(x)
__global__ __launch_bounds__(256) void k_cvtx(const float* __restrict__ x,
                                              unsigned short* __restrict__ xb) {
    int i = blockIdx.x * 256 + threadIdx.x;
    const float4* xp = (const float4*)x;
    float4 a = xp[i * 2], b = xp[i * 2 + 1];
    int4 o;
    o.x = (int)f2bf(a.x) | ((int)f2bf(a.y) << 16);
    o.y = (int)f2bf(a.z) | ((int)f2bf(a.w) << 16);
    o.z = (int)f2bf(b.x) | ((int)f2bf(b.y) << 16);
    o.w = (int)f2bf(b.z) | ((int)f2bf(b.w) << 16);
    ((int4*)xb)[i] = o;
}

// ---------------------------------------------------------------------------
// A0: coarse histogram of dst>>8 (LDS-aggregated)
__global__ __launch_bounds__(256) void k_histA(const int* __restrict__ ei,
                                               int* __restrict__ ccnt) {
    __shared__ int h[256];
    int t = threadIdx.x;
    h[t] = 0;
    __syncthreads();
    int idx = blockIdx.x * 1024 + t * 4;
    if (idx < N_EDGES) {  // N_EDGES % 4 == 0 -> whole int4 valid
        int4 d = *(const int4*)&ei[N_EDGES + idx];
        atomicAdd(&h[d.x >> 8], 1);
        atomicAdd(&h[d.y >> 8], 1);
        atomicAdd(&h[d.z >> 8], 1);
        atomicAdd(&h[d.w >> 8], 1);
    }
    __syncthreads();
    if (t < NCB && h[t]) atomicAdd(&ccnt[t], h[t]);
}

// ---------------------------------------------------------------------------
// A1: exclusive scan of ccnt[196] -> coff[197], gcur; row_off[N] = total
__global__ __launch_bounds__(256) void k_scanA1(const int* __restrict__ ccnt,
                                                int* __restrict__ coff,
                                                int* __restrict__ gcur,
                                                int* __restrict__ row_off) {
    int t = threadIdx.x;
    int v = (t < NCB) ? ccnt[t] : 0;
    int lane = t & 63, wv = t >> 6;
    int inc = v;
#pragma unroll
    for (int off = 1; off < 64; off <<= 1) {
        int y = __shfl_up(inc, off);
        if (lane >= off) inc += y;
    }
    __shared__ int ws4[4];
    if (lane == 63) ws4[wv] = inc;
    __syncthreads();
    int wb = 0;
    for (int i = 0; i < wv; ++i) wb += ws4[i];
    int ex = wb + inc - v;
    if (t < NCB) { coff[t] = ex; gcur[t] = ex; }
    if (t == NCB - 1) { coff[NCB] = ex + v; row_off[N_NODES] = ex + v; }
}

// ---------------------------------------------------------------------------
// A2: bucket edges into coarse segments; rec = src | rel<<16 | (dst&255)<<19
#define ACHUNK 2048
__global__ __launch_bounds__(256) void k_bucketA(const int* __restrict__ ei,
                                                 const int* __restrict__ et,
                                                 int* __restrict__ gcur,
                                                 unsigned int* __restrict__ recA) {
    __shared__ int lcnt[NCB], lbase[NCB];
    const int base = blockIdx.x * ACHUNK;
    const int t = threadIdx.x;
    if (t < NCB) lcnt[t] = 0;
    __syncthreads();
    unsigned int rec[8];
    int mb[8];
#pragma unroll
    for (int i = 0; i < 8; ++i) {
        int e = base + t + i * 256;
        if (e < N_EDGES) {
            int src = ei[e];
            int dst = ei[N_EDGES + e];
            int r = et[e];
            rec[i] = (unsigned)src | ((unsigned)r << 16) | ((unsigned)(dst & 255) << 19);
            mb[i] = dst >> 8;
            atomicAdd(&lcnt[mb[i]], 1);
        } else mb[i] = -1;
    }
    __syncthreads();
    if (t < NCB) lbase[t] = lcnt[t] ? atomicAdd(&gcur[t], lcnt[t]) : 0;
    __syncthreads();
    if (t < NCB) lcnt[t] = 0;
    __syncthreads();
#pragma unroll
    for (int i = 0; i < 8; ++i) {
        if (mb[i] < 0) continue;
        int pos = lbase[mb[i]] + atomicAdd(&lcnt[mb[i]], 1);
        recA[pos] = rec[i];
    }
}

// ---------------------------------------------------------------------------
// C: per coarse bucket, build per-dst CSR + row_off + dinv (all LDS atomics)
__global__ __launch_bounds__(256) void k_buildC(const unsigned int* __restrict__ recA,
                                                const int* __restrict__ coff,
                                                int* __restrict__ row_off,
                                                int* __restrict__ csr,
                                                float* __restrict__ dinv) {
    const int b = blockIdx.x, t = threadIdx.x;
    const int s0 = coff[b], s1 = coff[b + 1];
    __shared__ int h2[2048];   // (dst&255)*8 + rel
    __shared__ int cur[256];
    __shared__ int ws4[4];
    for (int i = t; i < 2048; i += 256) h2[i] = 0;
    __syncthreads();
    for (int i = s0 + t; i < s1; i += 256) {
        unsigned int p = recA[i];
        atomicAdd(&h2[((p >> 19) & 255) * 8 + ((p >> 16) & 7)], 1);
    }
    __syncthreads();
    int sum = 0;
#pragma unroll
    for (int r = 0; r < 8; ++r) sum += h2[t * 8 + r];
    int lane = t & 63, wv = t >> 6;
    int inc = sum;
#pragma unroll
    for (int off = 1; off < 64; off <<= 1) {
        int y = __shfl_up(inc, off);
        if (lane >= off) inc += y;
    }
    if (lane == 63) ws4[wv] = inc;
    __syncthreads();
    int wb = 0;
    for (int i = 0; i < wv; ++i) wb += ws4[i];
    int ex = wb + inc - sum;          // exclusive per-dst offset within bucket
    cur[t] = ex;
    int dst = (b << 8) + t;
    if (dst < N_NODES) row_off[dst] = s0 + ex;
    __syncthreads();
    for (int i = t; i < 2048; i += 256) {
        int d2 = (b << 8) + (i >> 3);
        if (d2 < N_NODES) dinv[(size_t)d2 * 8 + (i & 7)] = 1.0f / fmaxf((float)h2[i], 1.0f);
    }
    for (int i = s0 + t; i < s1; i += 256) {
        unsigned int p = recA[i];
        int pos = s0 + atomicAdd(&cur[(p >> 19) & 255], 1);
        csr[pos] = (int)(p & 0x7FFFF);   // src | rel<<16
    }
}

// ---------------------------------------------------------------------------
// fused bf16 MFMA GEMM, 9 panels: y<8 -> bf16 xW[.,y*128..], y==8 -> fp32 out
__global__ __launch_bounds__(256) void k_mm_big(const unsigned short* __restrict__ xb,
                                                const unsigned short* __restrict__ WbT,
                                                unsigned short* __restrict__ xW,
                                                float* __restrict__ out, int M) {
    __shared__ unsigned short As[64][136];
    __shared__ unsigned short Bs[128][136];
    const int rb = blockIdx.x * 64;
    const unsigned short* Bsrc = WbT + blockIdx.y * 16384;
    const int t = threadIdx.x;

#pragma unroll
    for (int i = 0; i < 4; ++i) {
        int f = t + i * 256;
        int row = f >> 4, c8 = (f & 15) << 3;
        int gr = rb + row;
        int4 v = make_int4(0, 0, 0, 0);
        if (gr < M) v = *(const int4*)&xb[gr * D + c8];
        *(int4*)&As[row][c8] = v;
    }
#pragma unroll
    for (int i = 0; i < 8; ++i) {
        int f = t + i * 256;
        int row = f >> 4, c8 = (f & 15) << 3;
        int4 v = *(const int4*)&Bsrc[row * 128 + c8];
        *(int4*)&Bs[row][c8] = v;
    }
    __syncthreads();

    const int lane = t & 63;
    const int w = t >> 6;
    const int lr = lane & 15;
    const int lg = lane >> 4;
    f32x4 acc[4][2] = {};
#pragma unroll
    for (int kk = 0; kk < 128; kk += 32) {
        int ko = kk + lg * 8;
        bf16x8 a[4], bvec[2];
#pragma unroll
        for (int m = 0; m < 4; ++m) a[m] = *(const bf16x8*)&As[m * 16 + lr][ko];
#pragma unroll
        for (int n = 0; n < 2; ++n) bvec[n] = *(const bf16x8*)&Bs[w * 32 + n * 16 + lr][ko];
#pragma unroll
        for (int m = 0; m < 4; ++m)
#pragma unroll
            for (int n = 0; n < 2; ++n)
                acc[m][n] = __builtin_amdgcn_mfma_f32_16x16x32_bf16(a[m], bvec[n], acc[m][n], 0, 0, 0);
    }

    const bool self = (blockIdx.y == 8);
#pragma unroll
    for (int m = 0; m < 4; ++m)
#pragma unroll
        for (int n = 0; n < 2; ++n)
#pragma unroll
            for (int q = 0; q < 4; ++q) {
                int grow = rb + m * 16 + lg * 4 + q;
                int colL = w * 32 + n * 16 + lr;
                if (grow < M) {
                    if (self) out[(size_t)grow * 128 + colL] = acc[m][n][q];
                    else      xW[(size_t)grow * 1024 + blockIdx.y * 128 + colL] = f2bf(acc[m][n][q]);
                }
            }
}

// ---------------------------------------------------------------------------
// small-path GEMM (unchanged semantics)
template <bool OB>
__global__ __launch_bounds__(256) void k_mm(const unsigned short* __restrict__ xb,
                                            const unsigned short* __restrict__ Bbase,
                                            unsigned short* __restrict__ Obf,
                                            float* __restrict__ Of,
                                            int ostride, int M) {
    __shared__ unsigned short As[64][136];
    __shared__ unsigned short Bs[128][136];
    const int rb = blockIdx.x * 64;
    const unsigned short* Bsrc = Bbase;
    const int t = threadIdx.x;
#pragma unroll
    for (int i = 0; i < 4; ++i) {
        int f = t + i * 256;
        int row = f >> 4, c8 = (f & 15) << 3;
        int gr = rb + row;
        int4 v = make_int4(0, 0, 0, 0);
        if (gr < M) v = *(const int4*)&xb[gr * D + c8];
        *(int4*)&As[row][c8] = v;
    }
#pragma unroll
    for (int i = 0; i < 8; ++i) {
        int f = t + i * 256;
        int row = f >> 4, c8 = (f & 15) << 3;
        int4 v = *(const int4*)&Bsrc[row * 128 + c8];
        *(int4*)&Bs[row][c8] = v;
    }
    __syncthreads();
    const int lane = t & 63;
    const int w = t >> 6;
    const int lr = lane & 15;
    const int lg = lane >> 4;
    f32x4 acc[4][2] = {};
#pragma unroll
    for (int kk = 0; kk < 128; kk += 32) {
        int ko = kk + lg * 8;
        bf16x8 a[4], bvec[2];
#pragma unroll
        for (int m = 0; m < 4; ++m) a[m] = *(const bf16x8*)&As[m * 16 + lr][ko];
#pragma unroll
        for (int n = 0; n < 2; ++n) bvec[n] = *(const bf16x8*)&Bs[w * 32 + n * 16 + lr][ko];
#pragma unroll
        for (int m = 0; m < 4; ++m)
#pragma unroll
            for (int n = 0; n < 2; ++n)
                acc[m][n] = __builtin_amdgcn_mfma_f32_16x16x32_bf16(a[m], bvec[n], acc[m][n], 0, 0, 0);
    }
#pragma unroll
    for (int m = 0; m < 4; ++m)
#pragma unroll
        for (int n = 0; n < 2; ++n)
#pragma unroll
            for (int q = 0; q < 4; ++q) {
                int grow = rb + m * 16 + lg * 4 + q;
                int col = w * 32 + n * 16 + lr;
                if (grow < M) {
                    if (OB) Obf[(size_t)grow * ostride + col] = f2bf(acc[m][n][q]);
                    else    Of[(size_t)grow * ostride + col] = acc[m][n][q];
                }
            }
}

// ---------------------------------------------------------------------------
// gather: 4 edge-groups x 32 lanes x 4 bf16 (uint2 loads), LDS reduce
__global__ __launch_bounds__(128) void k_gather(const unsigned short* __restrict__ xWall,
                                                const int* __restrict__ csr,
                                                const int* __restrict__ row_off,
                                                const float* __restrict__ dinv,
                                                float* __restrict__ out) {
    const int dst = blockIdx.x;
    const int t = threadIdx.x;
    const int s0 = row_off[dst], s1 = row_off[dst + 1];
    const int n = s1 - s0;
    if (n <= 0) return;
    __shared__ float sdinv[N_REL];
    __shared__ int epack[128];
    __shared__ float sacc[512];
    if (t < N_REL) sdinv[t] = dinv[(size_t)dst * 8 + t];
    const int g = t >> 5, l = t & 31;
    float4 acc = make_float4(0.f, 0.f, 0.f, 0.f);
    for (int base = 0; base < n; base += 128) {
        int m = min(n - base, 128);
        __syncthreads();
        if (t < m) epack[t] = csr[s0 + base + t];
        __syncthreads();
        for (int j = g; j < m; j += 4) {
            int p = epack[j];
            int src = p & 0xFFFF;
            int rel = (p >> 16) & 7;
            float s = sdinv[rel];
            uint2 v = *(const uint2*)&xWall[(size_t)src * 1024 + rel * 128 + l * 4];
            acc.x += s * __uint_as_float(v.x << 16);
            acc.y += s * __uint_as_float(v.x & 0xFFFF0000u);
            acc.z += s * __uint_as_float(v.y << 16);
            acc.w += s * __uint_as_float(v.y & 0xFFFF0000u);
        }
    }
    *(float4*)&sacc[t * 4] = acc;
    __syncthreads();
    float r = 0.f;
#pragma unroll
    for (int gg = 0; gg < 4; ++gg) r += sacc[(gg * 32 + (t >> 2)) * 4 + (t & 3)];
    out[(size_t)dst * D + t] += r;
}

// ---------------------------------------------------------------------------
// fallback: per-relation gather from xWr [N][128] bf16
__global__ __launch_bounds__(128) void k_gather_r(const unsigned short* __restrict__ xWr,
                                                  const int* __restrict__ csr,
                                                  const int* __restrict__ row_off,
                                                  const float* __restrict__ dinv,
                                                  float* __restrict__ out, int rel) {
    const int dst = blockIdx.x;
    const int t = threadIdx.x;
    __shared__ int epack[128];
    int s0 = row_off[dst], s1 = row_off[dst + 1];
    int n = s1 - s0;
    if (n <= 0) return;
    float dv = dinv[(size_t)dst * 8 + rel];
    float acc = 0.f;
    for (int base = 0; base < n; base += 128) {
        int m = min(n - base, 128);
        __syncthreads();
        if (t < m) epack[t] = csr[s0 + base + t];
        __syncthreads();
        for (int j = 0; j < m; ++j) {
            int p = epack[j];
            if (((p >> 16) & 7) != rel) continue;
            acc += bf2f((unsigned short)((const unsigned short*)xWr)[(size_t)(p & 0xFFFF) * 128 + t]);
        }
    }
    out[(size_t)dst * D + t] += acc * dv;
}

// ---------------------------------------------------------------------------
extern "C" void kernel_launch(void* const* d_in, const int* in_sizes, int n_in,
                              void* d_out, int out_size, void* d_ws, size_t ws_size,
                              hipStream_t stream) {
    const float* x         = (const float*)d_in[0];
    const float* bases     = (const float*)d_in[1];
    const float* coeff     = (const float*)d_in[2];
    const float* self_loop = (const float*)d_in[3];
    const int*   ei        = (const int*)d_in[4];
    const int*   et        = (const int*)d_in[5];
    float* out = (float*)d_out;

    char* ws = (char*)d_ws;
    size_t o = 0;
    auto alloc = [&](size_t bytes) { size_t r = o; o += (bytes + 255) & ~(size_t)255; return r; };
    size_t o_ccnt   = alloc(256 * 4);                        // zeroed
    size_t zero_end = o;
    size_t o_coff   = alloc((NCB + 1) * 4);
    size_t o_gcur   = alloc(NCB * 4);
    size_t o_rowoff = alloc((size_t)(N_NODES + 1) * 4);
    size_t o_recA   = alloc((size_t)N_EDGES * 4);
    size_t o_csr    = alloc((size_t)N_EDGES * 4);
    size_t o_dinv   = alloc((size_t)N_NODES * 8 * 4);
    size_t o_W      = alloc((size_t)N_REL * 16384 * 4);
    size_t o_WbT    = alloc((size_t)9 * 16384 * 2);
    size_t o_xb     = alloc((size_t)N_NODES * D * 2);
    size_t o_xW     = o;
    size_t need_big   = o + (size_t)N_NODES * 1024 * 2;
    size_t need_small = o + (size_t)N_NODES * 128 * 2;
    if (ws_size < need_small) return;
    bool big = (ws_size >= need_big);

    int*            ccnt    = (int*)(ws + o_ccnt);
    int*            coff    = (int*)(ws + o_coff);
    int*            gcur    = (int*)(ws + o_gcur);
    int*            row_off = (int*)(ws + o_rowoff);
    unsigned int*   recA    = (unsigned int*)(ws + o_recA);
    int*            csr     = (int*)(ws + o_csr);
    float*          dinv    = (float*)(ws + o_dinv);
    float*          W       = (float*)(ws + o_W);
    unsigned short* WbT     = (unsigned short*)(ws + o_WbT);
    unsigned short* xb      = (unsigned short*)(ws + o_xb);
    unsigned short* xW      = (unsigned short*)(ws + o_xW);

    hipMemsetAsync(ws, 0, zero_end, stream);

    k_compute_W<<<512, 256, 0, stream>>>(coeff, bases, W);
    k_transW<<<9, 256, 0, stream>>>(W, self_loop, WbT);
    k_cvtx<<<(N_NODES * D / 8 + 255) / 256, 256, 0, stream>>>(x, xb);

    k_histA<<<(N_EDGES + 1023) / 1024, 256, 0, stream>>>(ei, ccnt);
    k_scanA1<<<1, 256, 0, stream>>>(ccnt, coff, gcur, row_off);
    k_bucketA<<<(N_EDGES + ACHUNK - 1) / ACHUNK, 256, 0, stream>>>(ei, et, gcur, recA);
    k_buildC<<<NCB, 256, 0, stream>>>(recA, coff, row_off, csr, dinv);

    const int MB = (N_NODES + 63) / 64;  // 782

    if (big) {
        k_mm_big<<<dim3(MB, 9), 256, 0, stream>>>(xb, WbT, xW, out, N_NODES);
        k_gather<<<N_NODES, 128, 0, stream>>>(xW, csr, row_off, dinv, out);
    } else {
        k_mm<false><<<dim3(MB, 1), 256, 0, stream>>>(xb, WbT + 8 * 16384, nullptr, out, 128, N_NODES);
        for (int r = 0; r < N_REL; ++r) {
            k_mm<true><<<dim3(MB, 1), 256, 0, stream>>>(xb, WbT + r * 16384, xW, nullptr, 128, N_NODES);
            k_gather_r<<<N_NODES, 128, 0, stream>>>(xW, csr, row_off, dinv, out, r);
        }
    }
}